// Round 6
// baseline (1865.029 us; speedup 1.0000x reference)
//
#include <hip/hip_runtime.h>

#define LN_EPS 1e-5f
// -(LR * 2/H) = -(0.01 * 2/32): folds SGD lr and MSE-mean gradient factor
#define C1 (-6.25e-4f)

// 32-lane butterfly sum (lanes 0..31); result replicated in every lane.
__device__ __forceinline__ float red32(float x) {
  #pragma unroll
  for (int m = 1; m < 32; m <<= 1) x += __shfl_xor(x, m, 64);
  return x;
}

// ---------- kernel A: H[v] = LN(embed[v] + ff(embed[v])),  H dim = 32 ----------
__global__ __launch_bounds__(64) void pmm_build_H(
    const float* __restrict__ embed,  // [64][32]
    const float* __restrict__ fw1,    // [64][32]
    const float* __restrict__ fb1,    // [64]
    const float* __restrict__ fw2,    // [32][64]
    const float* __restrict__ fb2,    // [32]
    const float* __restrict__ lng,    // [32]
    const float* __restrict__ lnb,    // [32]
    float* __restrict__ H) {          // [64][32]
  const int v = blockIdx.x;   // vocab id 0..63
  const int t = threadIdx.x;  // 0..63 (one wave)
  __shared__ float e[32];
  __shared__ float r1[64];
  if (t < 32) e[t] = embed[v * 32 + t];
  __syncthreads();
  // fc1: 64 outputs (2H), output o = t
  float acc = fb1[t];
  #pragma unroll
  for (int h = 0; h < 32; ++h) acc = fmaf(e[h], fw1[t * 32 + h], acc);
  r1[t] = fmaxf(acc, 0.f);
  __syncthreads();
  if (t < 32) {
    float a2 = fb2[t];
    #pragma unroll
    for (int o = 0; o < 64; ++o) a2 = fmaf(r1[o], fw2[t * 64 + o], a2);
    float z = e[t] + a2;
    float s = z;
    #pragma unroll
    for (int m = 1; m < 32; m <<= 1) s += __shfl_xor(s, m, 64);
    float mu = s * (1.f / 32.f);
    float dz = z - mu;
    float q = dz * dz;
    #pragma unroll
    for (int m = 1; m < 32; m <<= 1) q += __shfl_xor(q, m, 64);
    float var = q * (1.f / 32.f);
    H[v * 32 + t] = dz / sqrtf(var + LN_EPS) * lng[t] + lnb[t];
  }
}

// ---------- kernel B: per-sample inner SGD loop (32 threads = 1 sample) ----------
__global__ __launch_bounds__(32) void pmm_inner(
    const void* __restrict__ seq_raw,   // int32 (int64 auto-detected)
    const float* __restrict__ H,        // [64][32] f32 table in ws
    const float* __restrict__ mw1,      // [8][32]
    const float* __restrict__ mb1,      // [8]
    const float* __restrict__ mw2,      // [32][8]
    const float* __restrict__ mb2,      // [32]
    const float* __restrict__ ow,       // [64][32]
    const float* __restrict__ ob,       // [64]
    float* __restrict__ out) {          // [256][64]
  const int b = blockIdx.x;     // sample
  const int c = threadIdx.x;    // 0..31, owns hidden column c

  __shared__ float Hs[64 * 32];    // 8 KB
  __shared__ float OWp[64 * 33];   // out_w padded to stride 33 (bank-conflict-free)
  __shared__ float ctx[32];

  const int* __restrict__ s32 = (const int*)seq_raw;
  // int64 detection: values 0..63 => under int64 every odd int32 word of
  // sample 0 is zero. Reads first 16 KB only (safe for both widths).
  int accv = 0;
  #pragma unroll
  for (int q = 0; q < 64; ++q) accv |= s32[2 * (c * 64 + q) + 1];
  const bool is64 = (__ballot(accv != 0) == 0ULL);

  // stage H table: 2048 floats = 512 float4
  #pragma unroll
  for (int m = 0; m < 16; ++m) {
    ((float4*)Hs)[m * 32 + c] = ((const float4*)H)[m * 32 + c];
  }
  // stage out_w with +1 padding: coalesced global, scattered LDS
  #pragma unroll
  for (int m = 0; m < 64; ++m) {
    const int idx = m * 32 + c;          // 0..2047
    OWp[(idx >> 5) * 33 + (idx & 31)] = ow[idx];
  }

  // per-lane parameter slices
  float W1L[8], W2L[8], B1[8];
  #pragma unroll
  for (int i = 0; i < 8; ++i) {
    W1L[i] = mw1[i * 32 + c];   // w1[i][c]
    W2L[i] = mw2[c * 8 + i];    // w2[c][i]
    B1[i]  = mb1[i];            // replicated
  }
  float b2L = mb2[c];
  const int base = b * 4096;
  __syncthreads();

  auto IDX = [&](int pos) -> int {
    return is64 ? s32[(base + pos) << 1] : s32[base + pos];
  };
  auto PF = [&](int m, float2& kv) {
    kv.x = Hs[IDX(2 * m) * 32 + c];      // key column c
    kv.y = Hs[IDX(2 * m + 1) * 32 + c];  // val column c
  };

  auto STEP = [&](const float2& kv) {
    float z1[8], a1[8];
    #pragma unroll
    for (int i = 0; i < 8; ++i) {
      z1[i] = red32(W1L[i] * kv.x) + B1[i];  // w1[i]·k + b1[i], replicated
      a1[i] = fmaxf(z1[i], 0.f);
    }
    float r = b2L;                  // pred[c] - v[c]
    #pragma unroll
    for (int i = 0; i < 8; ++i) r = fmaf(W2L[i], a1[i], r);
    r -= kv.y;
    float m8[8];                    // sum_c w2[c][i]*r_c with OLD w2
    #pragma unroll
    for (int i = 0; i < 8; ++i) m8[i] = red32(W2L[i] * r);
    const float q = C1 * r;         // = -LR * (2/32) * r_c
    #pragma unroll
    for (int i = 0; i < 8; ++i) W2L[i] = fmaf(q, a1[i], W2L[i]);
    b2L += q;
    #pragma unroll
    for (int i = 0; i < 8; ++i) {
      const float dl = (z1[i] > 0.f) ? C1 * m8[i] : 0.f;
      B1[i]  += dl;
      W1L[i] = fmaf(dl, kv.x, W1L[i]);
    }
  };

  // 2047 steps, 2-slot software pipeline
  float2 s0, s1;
  PF(0, s0);
  for (int m = 0; m < 2046; m += 2) {
    PF(m + 1, s1);
    STEP(s0);
    PF(m + 2, s0);
    STEP(s1);
  }
  STEP(s0);  // step 2046

  // epilogue: ctx = mlp(final params, H[seq[4095]]); out = ctx @ ow^T + ob
  {
    const float kq = Hs[IDX(4095) * 32 + c];
    float a1[8];
    #pragma unroll
    for (int i = 0; i < 8; ++i) {
      a1[i] = fmaxf(red32(W1L[i] * kq) + B1[i], 0.f);
    }
    float p = b2L;
    #pragma unroll
    for (int i = 0; i < 8; ++i) p = fmaf(W2L[i], a1[i], p);
    ctx[c] = p;                    // lane c holds ctx[c]
    __syncthreads();
    #pragma unroll
    for (int h = 0; h < 2; ++h) {
      const int v = c + 32 * h;    // vocab outputs c and c+32
      float acc = ob[v];
      #pragma unroll
      for (int j = 0; j < 32; ++j) acc = fmaf(OWp[v * 33 + j], ctx[j], acc);
      out[b * 64 + v] = acc;
    }
  }
}

extern "C" void kernel_launch(void* const* d_in, const int* in_sizes, int n_in,
                              void* d_out, int out_size, void* d_ws, size_t ws_size,
                              hipStream_t stream) {
  const void*  seq   = d_in[0];
  const float* embed = (const float*)d_in[1];
  const float* fw1   = (const float*)d_in[2];
  const float* fb1   = (const float*)d_in[3];
  const float* fw2   = (const float*)d_in[4];
  const float* fb2   = (const float*)d_in[5];
  const float* lng   = (const float*)d_in[6];
  const float* lnb   = (const float*)d_in[7];
  const float* mw1   = (const float*)d_in[8];
  const float* mb1   = (const float*)d_in[9];
  const float* mw2   = (const float*)d_in[10];
  const float* mb2   = (const float*)d_in[11];
  const float* ow    = (const float*)d_in[12];
  const float* ob    = (const float*)d_in[13];
  float* out = (float*)d_out;
  float* H   = (float*)d_ws;  // 64*32 f32 table

  pmm_build_H<<<64, 64, 0, stream>>>(embed, fw1, fb1, fw2, fb2, lng, lnb, H);
  pmm_inner<<<256, 32, 0, stream>>>(seq, H, mw1, mb1, mw2, mb2, ow, ob, out);
}

// Round 7
// 710.512 us; speedup vs baseline: 2.6249x; 2.6249x over previous
//
#include <hip/hip_runtime.h>

#define LN_EPS 1e-5f
// -(LR * 2/H) = -(0.01 * 2/32): folds SGD lr and MSE-mean gradient factor
#define C1 (-6.25e-4f)

// ---------- cross-lane helpers ----------
template<int CTRL>
__device__ __forceinline__ float dppAdd(float x) {
  int s = __builtin_amdgcn_update_dpp(0, __float_as_int(x), CTRL, 0xF, 0xF, true);
  return x + __int_as_float(s);
}

// Sum over each 32-lane half; result replicated within the half.
// 4 DPP VALU stages + 1 ds_swizzle (xor16). Semantics HW-validated in r2/r5
// (bit-identical results vs shfl_xor implementation).
__device__ __forceinline__ float redHalf(float x) {
  x = dppAdd<0xB1>(x);    // quad_perm(1,0,3,2): xor 1
  x = dppAdd<0x4E>(x);    // quad_perm(2,3,0,1): xor 2
  x = dppAdd<0x124>(x);   // row_ror:4 (quads uniform -> adds other quad pair)
  x = dppAdd<0x128>(x);   // row_ror:8 -> row-of-16 sum replicated
  x = x + __int_as_float(__builtin_amdgcn_ds_swizzle(__float_as_int(x), 0x401F)); // xor16
  return x;
}

// ---------- kernel A: H[v] = LN(embed[v] + ff(embed[v])), H dim = 32 ----------
__global__ __launch_bounds__(64) void pmm_build_H(
    const float* __restrict__ embed,  // [64][32]
    const float* __restrict__ fw1,    // [64][32]
    const float* __restrict__ fb1,    // [64]
    const float* __restrict__ fw2,    // [32][64]
    const float* __restrict__ fb2,    // [32]
    const float* __restrict__ lng,    // [32]
    const float* __restrict__ lnb,    // [32]
    float* __restrict__ H) {          // [64][32]
  const int v = blockIdx.x;
  const int t = threadIdx.x;
  __shared__ float e[32];
  __shared__ float r1[64];
  if (t < 32) e[t] = embed[v * 32 + t];
  __syncthreads();
  float acc = fb1[t];
  #pragma unroll
  for (int h = 0; h < 32; ++h) acc = fmaf(e[h], fw1[t * 32 + h], acc);
  r1[t] = fmaxf(acc, 0.f);
  __syncthreads();
  if (t < 32) {
    float a2 = fb2[t];
    #pragma unroll
    for (int o = 0; o < 64; ++o) a2 = fmaf(r1[o], fw2[t * 64 + o], a2);
    float z = e[t] + a2;
    float s = z;
    #pragma unroll
    for (int m = 1; m < 32; m <<= 1) s += __shfl_xor(s, m, 64);
    float mu = s * (1.f / 32.f);
    float dz = z - mu;
    float q = dz * dz;
    #pragma unroll
    for (int m = 1; m < 32; m <<= 1) q += __shfl_xor(q, m, 64);
    float var = q * (1.f / 32.f);
    H[v * 32 + t] = dz / sqrtf(var + LN_EPS) * lng[t] + lnb[t];
  }
}

// ---------- kernel B: per-sample inner SGD loop, full 64-lane wave ----------
// Lanes l and l^32 both own column c=l&31 (mirrored k/v); half h=l>>5 owns
// hidden units i = 4h..4h+3. Trees run per-half (both halves in one instr).
__global__ __launch_bounds__(64) void pmm_inner(
    const void* __restrict__ seq_raw,   // int32 (int64 auto-detected)
    const float* __restrict__ H,        // [64][32] f32 table in ws
    const float* __restrict__ mw1,      // [8][32]
    const float* __restrict__ mb1,      // [8]
    const float* __restrict__ mw2,      // [32][8]
    const float* __restrict__ mb2,      // [32]
    const float* __restrict__ ow,       // [64][32]
    const float* __restrict__ ob,       // [64]
    float* __restrict__ out) {          // [256][64]
  const int b = blockIdx.x;
  const int l = threadIdx.x;    // 0..63
  const int c = l & 31;         // hidden column
  const int h = l >> 5;         // half: local hidden units 4h..4h+3

  __shared__ float Hs[64 * 32];    // 8 KB
  __shared__ int   seqs[4096];     // 16 KB: this sample's indices
  __shared__ float OWp[64 * 33];   // out_w, stride-33 padded
  __shared__ float ctxs[32];

  const int* __restrict__ s32 = (const int*)seq_raw;
  // int64 detection: values 0..63 => under int64 every odd int32 word of
  // sample 0 is zero. Reads first 16 KB only (safe for both widths).
  int accv = 0;
  #pragma unroll
  for (int q = 0; q < 32; ++q) accv |= s32[2 * (l * 32 + q) + 1];
  const bool is64 = (__ballot(accv != 0) == 0ULL);

  // stage this sample's seq slice
  const int base = b * 4096;
  if (!is64) {
    #pragma unroll
    for (int m = 0; m < 16; ++m)
      ((int4*)seqs)[m * 64 + l] = ((const int4*)(s32 + base))[m * 64 + l];
  } else {
    #pragma unroll
    for (int m = 0; m < 64; ++m)
      seqs[m * 64 + l] = s32[(base + m * 64 + l) << 1];  // low word (LE)
  }

  // stage H table: 2048 floats = 512 float4
  #pragma unroll
  for (int m = 0; m < 8; ++m)
    ((float4*)Hs)[m * 64 + l] = ((const float4*)H)[m * 64 + l];
  // stage out_w padded (elements of one float4 stay in one row: idx%32<=28)
  #pragma unroll
  for (int m = 0; m < 8; ++m) {
    float4 x = ((const float4*)ow)[m * 64 + l];
    const int idx = (m * 64 + l) * 4;
    const int r = idx >> 5, cc = idx & 31;
    OWp[r * 33 + cc]     = x.x;
    OWp[r * 33 + cc + 1] = x.y;
    OWp[r * 33 + cc + 2] = x.z;
    OWp[r * 33 + cc + 3] = x.w;
  }

  // per-lane parameters: local W1 rows, W2 row c in local-first order
  float W1L[4], B1L[4], W2o[8];
  #pragma unroll
  for (int j = 0; j < 4; ++j) {
    W1L[j] = mw1[(4 * h + j) * 32 + c];
    B1L[j] = mb1[4 * h + j];
  }
  #pragma unroll
  for (int j = 0; j < 8; ++j) {
    const int i = (j < 4) ? (4 * h + j) : (4 * (1 - h) + (j - 4));
    W2o[j] = mw2[c * 8 + i];   // j<4: local units, j>=4: remote units
  }
  float b2L = mb2[c];
  __syncthreads();

  auto PF = [&](int m, float2& kv) {
    const int ik = seqs[2 * m], iv = seqs[2 * m + 1];
    kv.x = Hs[ik * 32 + c];
    kv.y = Hs[iv * 32 + c];
  };

  auto STEP = [&](const float2& kv) {
    float z1[4], a1l[4], a1r[4];
    #pragma unroll
    for (int j = 0; j < 4; ++j) {
      z1[j] = redHalf(W1L[j] * kv.x) + B1L[j];  // w1[i].k + b1[i], i local
      a1l[j] = fmaxf(z1[j], 0.f);
    }
    #pragma unroll
    for (int j = 0; j < 4; ++j) a1r[j] = __shfl_xor(a1l[j], 32, 64);
    float r = b2L;                  // pred[c] - v[c] (same in both halves
    #pragma unroll                  //  up to ULP ordering)
    for (int j = 0; j < 4; ++j) r = fmaf(W2o[j], a1l[j], r);
    #pragma unroll
    for (int j = 0; j < 4; ++j) r = fmaf(W2o[4 + j], a1r[j], r);
    r -= kv.y;
    float m8[4];                    // sum_c w2[c][i]*r_c, i local, OLD w2
    #pragma unroll
    for (int j = 0; j < 4; ++j) m8[j] = redHalf(W2o[j] * r);
    const float q = C1 * r;
    #pragma unroll
    for (int j = 0; j < 4; ++j) W2o[j]     = fmaf(q, a1l[j], W2o[j]);
    #pragma unroll
    for (int j = 0; j < 4; ++j) W2o[4 + j] = fmaf(q, a1r[j], W2o[4 + j]);
    b2L += q;
    #pragma unroll
    for (int j = 0; j < 4; ++j) {
      const float dl = (z1[j] > 0.f) ? C1 * m8[j] : 0.f;
      B1L[j] += dl;
      W1L[j] = fmaf(dl, kv.x, W1L[j]);
    }
  };

  // 2047 steps, 2-slot software pipeline (kv prefetched 1 step ahead)
  float2 s0, s1;
  PF(0, s0);
  for (int m = 0; m < 2046; m += 2) {
    PF(m + 1, s1);
    STEP(s0);
    PF(m + 2, s0);
    STEP(s1);
  }
  STEP(s0);  // step 2046

  // epilogue: ctx = mlp(final params, H[seq[4095]]); out = ctx @ ow^T + ob
  {
    const int ik = seqs[4095];
    const float kq = Hs[ik * 32 + c];
    float a1l[4], a1r[4];
    #pragma unroll
    for (int j = 0; j < 4; ++j)
      a1l[j] = fmaxf(redHalf(W1L[j] * kq) + B1L[j], 0.f);
    #pragma unroll
    for (int j = 0; j < 4; ++j) a1r[j] = __shfl_xor(a1l[j], 32, 64);
    float p = b2L;
    #pragma unroll
    for (int j = 0; j < 4; ++j) p = fmaf(W2o[j], a1l[j], p);
    #pragma unroll
    for (int j = 0; j < 4; ++j) p = fmaf(W2o[4 + j], a1r[j], p);
    if (l < 32) ctxs[c] = p;   // half A order == global i order
    __syncthreads();
    float acc = ob[l];
    #pragma unroll
    for (int j = 0; j < 32; ++j) acc = fmaf(OWp[l * 33 + j], ctxs[j], acc);
    out[b * 64 + l] = acc;
  }
}

extern "C" void kernel_launch(void* const* d_in, const int* in_sizes, int n_in,
                              void* d_out, int out_size, void* d_ws, size_t ws_size,
                              hipStream_t stream) {
  const void*  seq   = d_in[0];
  const float* embed = (const float*)d_in[1];
  const float* fw1   = (const float*)d_in[2];
  const float* fb1   = (const float*)d_in[3];
  const float* fw2   = (const float*)d_in[4];
  const float* fb2   = (const float*)d_in[5];
  const float* lng   = (const float*)d_in[6];
  const float* lnb   = (const float*)d_in[7];
  const float* mw1   = (const float*)d_in[8];
  const float* mb1   = (const float*)d_in[9];
  const float* mw2   = (const float*)d_in[10];
  const float* mb2   = (const float*)d_in[11];
  const float* ow    = (const float*)d_in[12];
  const float* ob    = (const float*)d_in[13];
  float* out = (float*)d_out;
  float* H   = (float*)d_ws;  // 64*32 f32 table

  pmm_build_H<<<64, 64, 0, stream>>>(embed, fw1, fb1, fw2, fb2, lng, lnb, H);
  pmm_inner<<<256, 64, 0, stream>>>(seq, H, mw1, mb1, mw2, mb2, ow, ob, out);
}